// Round 17
// baseline (88.820 us; speedup 1.0000x reference)
//
#include <hip/hip_runtime.h>

#define BATCH 4
#define NPTS  8192
#define FDIM  64
#define BK    64
#define NT    (NPTS / BK)

typedef _Float16 half_t;
typedef half_t half8  __attribute__((ext_vector_type(8)));
typedef half_t half2v __attribute__((ext_vector_type(2)));
typedef float  f32x4  __attribute__((ext_vector_type(4)));
typedef float  f32x16 __attribute__((ext_vector_type(16)));
typedef unsigned uint4v __attribute__((ext_vector_type(4)));
typedef unsigned uint2v __attribute__((ext_vector_type(2)));

__device__ inline unsigned pkrtz(float a, float b) {
    return __builtin_bit_cast(unsigned, __builtin_amdgcn_cvt_pkrtz(a, b));
}
__device__ inline half2v h2(unsigned u) { return __builtin_bit_cast(half2v, u); }

// swap(a,b): new a = [a.lo | b.lo], new b = [a.hi | b.hi]  (lane halves)
__device__ inline uint2v plswap(unsigned a, unsigned b) {
    return __builtin_amdgcn_permlane32_swap(a, b, false, false);
}

// ---------------- prep (merged): blocks 0..511 = support GEMM, 512..639 = cast+norm.
// gemm: one thread per (b, n, o-block16); w[64][16] in LDS (broadcast f32x4 reads).
// cast: ka fragment-major (elem (n, f=f8*8+j) at ((n>>6)*8+f8)*512 + (n&63)*8 + j) + nrm.
__global__ __launch_bounds__(256) void prep_kernel(
    const float* __restrict__ x, const float* __restrict__ w,
    half_t* __restrict__ ka, half_t* __restrict__ vt, float* __restrict__ nrm)
{
    int t = threadIdx.x;
    if (blockIdx.x < 512) {
        __shared__ float wl[FDIM * 16];
        int ob  = blockIdx.x & 3;                     // o-block (wave-uniform)
        int nch = blockIdx.x >> 2;                    // 128 chunks of 256 n
        #pragma unroll
        for (int i = 0; i < 4; ++i) {                 // stage w[:, ob*16:+16]
            int idx = i * 256 + t;                    // idx = f*16 + j
            wl[idx] = w[(idx >> 4) * FDIM + ob * 16 + (idx & 15)];
        }
        __syncthreads();

        int gid = nch * 256 + t;                      // (b, n)
        int b = gid >> 13;
        int n = gid & (NPTS - 1);
        const float* xb = x + (size_t)b * FDIM * NPTS + n;

        float acc[16];
        #pragma unroll
        for (int o = 0; o < 16; ++o) acc[o] = 0.0f;
        #pragma unroll
        for (int f = 0; f < FDIM; ++f) {
            float xv = xb[(size_t)f * NPTS];          // coalesced; L2-served re-read
            const f32x4* wr = (const f32x4*)&wl[f * 16];   // broadcast, conflict-free
            f32x4 w0 = wr[0], w1 = wr[1], w2 = wr[2], w3 = wr[3];
            acc[ 0] += xv * w0[0]; acc[ 1] += xv * w0[1];
            acc[ 2] += xv * w0[2]; acc[ 3] += xv * w0[3];
            acc[ 4] += xv * w1[0]; acc[ 5] += xv * w1[1];
            acc[ 6] += xv * w1[2]; acc[ 7] += xv * w1[3];
            acc[ 8] += xv * w2[0]; acc[ 9] += xv * w2[1];
            acc[10] += xv * w2[2]; acc[11] += xv * w2[3];
            acc[12] += xv * w3[0]; acc[13] += xv * w3[1];
            acc[14] += xv * w3[2]; acc[15] += xv * w3[3];
        }
        half_t* vb = vt + (size_t)b * FDIM * NPTS + (size_t)ob * 16 * NPTS + n;
        #pragma unroll
        for (int o = 0; o < 16; ++o)
            vb[(size_t)o * NPTS] = (half_t)acc[o];    // coalesced across lanes
    } else {
        int gid = (blockIdx.x - 512) * 256 + t;       // (b, n)
        int b = gid >> 13;
        int n = gid & (NPTS - 1);
        const float* xb = x + (size_t)b * FDIM * NPTS + n;

        float nr = 0.0f;
        half_t* kab = ka + (size_t)(gid >> 6) * 4096 + (size_t)(gid & 63) * 8;
        #pragma unroll
        for (int f8 = 0; f8 < 8; ++f8) {
            half8 h;
            #pragma unroll
            for (int j = 0; j < 8; ++j) {
                float xv = xb[(size_t)(f8 * 8 + j) * NPTS];   // coalesced
                nr += xv * xv;
                h[j] = (half_t)xv;
            }
            *(half8*)(kab + f8 * 512) = h;                    // contiguous 16B
        }
        nrm[gid] = nr * 1.44269504f;
    }
}

// ---------------- flash attention (R15-exact + T5 setprio):
// 32x32 MFMA, fixed-max softmax, split-KV; __launch_bounds__(256,2), grid 512,
// fp16 partials (qt-paired full-line stores). K/Q fragments direct from global
// (fragment-major), V in LDS dbuf. Each SIMD hosts 2 waves from DIFFERENT
// blocks (unsynchronized) -> setprio(1) around MFMA clusters arbitrates the
// MFMA-entering wave over the other wave's VALU issue (T5 mechanism, m191).
// (R8: (256,3) breaks blk->XCD packing. R11: (512,4) reg-caps -> spill.)
template<int SPLIT>
__global__ __launch_bounds__(256, 2) void flash_kernel(
    const half_t* __restrict__ qk, const half_t* __restrict__ vt,
    const float* __restrict__ nrm, float* __restrict__ out,
    half_t* __restrict__ part, float* __restrict__ lbuf)
{
    constexpr int TPS   = NT / SPLIT;
    constexpr int TOTAL = BATCH * SPLIT * (NPTS / 256);

    __shared__ half_t vl[2][BK * FDIM];    // V^T tile [o][granule-swizzled kv]

    int t    = threadIdx.x;
    int lane = t & 63;
    int l31  = lane & 31;
    int hi   = lane >> 5;
    int w    = t >> 6;                     // wave 0..3

    int blk0 = blockIdx.x;
    int blk  = (blk0 & 7) * (TOTAL / 8) + (blk0 >> 3);   // XCD swizzle (TOTAL%8==0)
    int qc   = blk & 31;                                 // q chunk (256 rows)
    int rest = blk >> 5;
    int s    = rest & (SPLIT - 1);
    int b    = rest / SPLIT;
    int qw   = qc * 256 + w * 64;                        // 64 q rows per wave

    const half_t* kg = qk + (size_t)b * NPTS * FDIM;     // fragment-major ka, batch b
    const half_t* vg = vt + (size_t)b * FDIM * NPTS;

    // Q B-frags (pre-scaled by log2 e) from fragment-major layout
    const half_t* qgb = kg + (size_t)(qw >> 6) * 4096 + (size_t)l31 * 8;
    half8 qf[2][4];
    #pragma unroll
    for (int qt = 0; qt < 2; ++qt)
        #pragma unroll
        for (int c = 0; c < 4; ++c) {
            qf[qt][c] = *(const half8*)(qgb + (c*2 + hi) * 512 + qt * 256);
            qf[qt][c] = qf[qt][c] * (half_t)1.44269504f;
        }

    float m2[2];
    #pragma unroll
    for (int qt = 0; qt < 2; ++qt)
        m2[qt] = nrm[(size_t)b * NPTS + qw + qt*32 + l31];

    // V staging: 512 16B-chunks, 2 per thread; swizzled LDS dest
    int r0 = t >> 3, g0 = t & 7;
    int r1 = r0 + 32;
    int li0 = r0 * FDIM + ((g0 ^ (r0 & 7)) * 8);
    int li1 = r1 * FDIM + ((g0 ^ (r1 & 7)) * 8);

    int kb0 = s * TPS * BK;
    half8 s2 = *(const half8*)(vg + (size_t)r0 * NPTS + kb0 + g0*8);
    half8 s3 = *(const half8*)(vg + (size_t)r1 * NPTS + kb0 + g0*8);

    // K fragments for tile 0 (direct global, coalesced)
    half8 kf[2][4];
    {
        const half_t* kgb = kg + (size_t)(kb0 >> 6) * 4096 + (size_t)l31 * 8;
        #pragma unroll
        for (int ct = 0; ct < 2; ++ct)
            #pragma unroll
            for (int c = 0; c < 4; ++c)
                kf[ct][c] = *(const half8*)(kgb + (c*2 + hi) * 512 + ct * 256);
    }

    f32x16 O[2][2];
    #pragma unroll
    for (int ot = 0; ot < 2; ++ot)
        #pragma unroll
        for (int qt = 0; qt < 2; ++qt)
            #pragma unroll
            for (int r = 0; r < 16; ++r) O[ot][qt][r] = 0.0f;
    float lsum[2] = {0.0f, 0.0f};

    for (int tt = 0; tt < TPS; ++tt) {
        half_t* vlb = vl[tt & 1];
        *(half8*)(vlb + li0) = s2;
        *(half8*)(vlb + li1) = s3;
        if (tt + 1 < TPS) {                // V prefetch stays in flight across barrier
            int kb = kb0 + (tt + 1) * BK;
            s2 = *(const half8*)(vg + (size_t)r0 * NPTS + kb + g0*8);
            s3 = *(const half8*)(vg + (size_t)r1 * NPTS + kb + g0*8);
        }
        __syncthreads();                   // V writes visible; prev-tile readers done

        const half_t* kgbn = kg + (size_t)((kb0 + (tt + 1) * BK) >> 6) * 4096 + (size_t)l31 * 8;

        // ---- S^T = K x Q^T for BOTH ct (C preset to -m2 folds max subtraction)
        f32x16 S[2][2];
        #pragma unroll
        for (int ct = 0; ct < 2; ++ct)
            #pragma unroll
            for (int r = 0; r < 16; ++r) { S[ct][0][r] = -m2[0]; S[ct][1][r] = -m2[1]; }
        __builtin_amdgcn_s_setprio(1);
        #pragma unroll
        for (int ct = 0; ct < 2; ++ct)
            #pragma unroll
            for (int c = 0; c < 4; ++c) {
                S[ct][0] = __builtin_amdgcn_mfma_f32_32x32x16_f16(kf[ct][c], qf[0][c], S[ct][0], 0, 0, 0);
                S[ct][1] = __builtin_amdgcn_mfma_f32_32x32x16_f16(kf[ct][c], qf[1][c], S[ct][1], 0, 0, 0);
            }
        __builtin_amdgcn_s_setprio(0);
        // refill kf (both ct) for next tile; L2 latency hides under exp/pack + PV
        if (tt + 1 < TPS) {
            #pragma unroll
            for (int ct = 0; ct < 2; ++ct)
                #pragma unroll
                for (int c = 0; c < 4; ++c)
                    kf[ct][c] = *(const half8*)(kgbn + (c*2 + hi) * 512 + ct * 256);
        }

        #pragma unroll
        for (int ct = 0; ct < 2; ++ct) {
            // ---- p = exp2(S); pack to fp16 (RTZ saturates); lsum via packed fp16 adds
            unsigned pk[2][8];
            #pragma unroll
            for (int qt = 0; qt < 2; ++qt) {
                #pragma unroll
                for (int rr = 0; rr < 8; ++rr)
                    pk[qt][rr] = pkrtz(__builtin_amdgcn_exp2f(S[ct][qt][2*rr]),
                                       __builtin_amdgcn_exp2f(S[ct][qt][2*rr+1]));
                half2v s2v = ((h2(pk[qt][0]) + h2(pk[qt][1])) + (h2(pk[qt][2]) + h2(pk[qt][3])))
                           + ((h2(pk[qt][4]) + h2(pk[qt][5])) + (h2(pk[qt][6]) + h2(pk[qt][7])));
                lsum[qt] += (float)s2v[0] + (float)s2v[1];
            }

            // ---- O^T += V^T x P^T for kt = 2ct, 2ct+1 (pk for this ct only)
            #pragma unroll
            for (int ktl = 0; ktl < 2; ++ktl) {
                const int kt = ct * 2 + ktl, i0 = ktl * 4;
                half8 pb[2];
                #pragma unroll
                for (int qt = 0; qt < 2; ++qt) {
                    uint2v r02 = plswap(pk[qt][i0+0], pk[qt][i0+2]);
                    uint2v r13 = plswap(pk[qt][i0+1], pk[qt][i0+3]);
                    uint4v uu; uu[0] = r02[0]; uu[1] = r13[0]; uu[2] = r02[1]; uu[3] = r13[1];
                    pb[qt] = __builtin_bit_cast(half8, uu);
                }
                int vrow0 = l31, vrow1 = 32 + l31;
                half8 vf0 = *(const half8*)(vlb + vrow0 * FDIM + (((2*kt + hi) ^ (vrow0 & 7)) * 8));
                half8 vf1 = *(const half8*)(vlb + vrow1 * FDIM + (((2*kt + hi) ^ (vrow1 & 7)) * 8));
                __builtin_amdgcn_s_setprio(1);
                O[0][0] = __builtin_amdgcn_mfma_f32_32x32x16_f16(vf0, pb[0], O[0][0], 0, 0, 0);
                O[0][1] = __builtin_amdgcn_mfma_f32_32x32x16_f16(vf0, pb[1], O[0][1], 0, 0, 0);
                O[1][0] = __builtin_amdgcn_mfma_f32_32x32x16_f16(vf1, pb[0], O[1][0], 0, 0, 0);
                O[1][1] = __builtin_amdgcn_mfma_f32_32x32x16_f16(vf1, pb[1], O[1][1], 0, 0, 0);
                __builtin_amdgcn_s_setprio(0);
            }
        }
    }

    // final row-sum reduce across lane halves (cols duplicated at l31 / l31+32)
    lsum[0] += __shfl_xor(lsum[0], 32);
    lsum[1] += __shfl_xor(lsum[1], 32);

    if constexpr (SPLIT == 1) {
        float inv[2] = {1.0f / lsum[0], 1.0f / lsum[1]};
        size_t ob = (size_t)b * FDIM * NPTS;
        #pragma unroll
        for (int qt = 0; qt < 2; ++qt)
            #pragma unroll
            for (int ot = 0; ot < 2; ++ot)
                #pragma unroll
                for (int r = 0; r < 16; ++r) {
                    int o = ot*32 + (r & 3) + 8*(r >> 2) + 4*hi;
                    out[ob + (size_t)o * NPTS + qw + qt*32 + l31] = O[ot][qt][r] * inv[qt];
                }
    } else {
        // fp16 partials; qt=0/qt=1 stores adjacent -> 64 consecutive fp16 (128B line)
        half_t* pbase = part + (size_t)(s * BATCH + b) * FDIM * NPTS;
        #pragma unroll
        for (int ot = 0; ot < 2; ++ot)
            #pragma unroll
            for (int r = 0; r < 16; ++r) {
                int o = ot*32 + (r & 3) + 8*(r >> 2) + 4*hi;
                half_t* po = pbase + (size_t)o * NPTS + qw + l31;
                po[0]  = (half_t)O[ot][0][r];
                po[32] = (half_t)O[ot][1][r];
            }
        if (hi == 0) {
            float* lb = lbuf + (size_t)(s * BATCH + b) * NPTS + qw;
            lb[l31]      = lsum[0];
            lb[32 + l31] = lsum[1];
        }
    }
}

// ---------------- combine: out = sum_s part_s / sum_s l_s (shared fixed max -> linear)
template<int SPLIT>
__global__ __launch_bounds__(256) void combine_kernel(
    const half_t* __restrict__ part, const float* __restrict__ lbuf,
    float* __restrict__ out)
{
    int gid  = blockIdx.x * 256 + threadIdx.x;    // B*F*N/8 threads
    int q8   = gid & (NPTS/8 - 1);
    int rest = gid >> 10;                         // b*64 + o
    int b    = rest >> 6;
    int o    = rest & 63;
    size_t ro = (size_t)rest * NPTS + (size_t)q8 * 8;

    float acc[8], ls[8];
    #pragma unroll
    for (int j = 0; j < 8; ++j) { acc[j] = 0.0f; ls[j] = 0.0f; }
    #pragma unroll
    for (int s = 0; s < SPLIT; ++s) {
        half8 pv = *(const half8*)(part + (size_t)(s * BATCH + b) * FDIM * NPTS
                                        + (size_t)o * NPTS + (size_t)q8 * 8);
        const float* lb = lbuf + (size_t)(s * BATCH + b) * NPTS + (size_t)q8 * 8;
        #pragma unroll
        for (int j = 0; j < 8; ++j) { acc[j] += (float)pv[j]; ls[j] += lb[j]; }
    }
    #pragma unroll
    for (int j = 0; j < 8; ++j) acc[j] /= ls[j];
    *(f32x4*)(out + ro)     = *(f32x4*)&acc[0];
    *(f32x4*)(out + ro + 4) = *(f32x4*)&acc[4];
}

extern "C" void kernel_launch(void* const* d_in, const int* in_sizes, int n_in,
                              void* d_out, int out_size, void* d_ws, size_t ws_size,
                              hipStream_t stream) {
    (void)in_sizes; (void)n_in; (void)out_size;
    const float* x = (const float*)d_in[0];
    const float* w = (const float*)d_in[1];
    float* out = (float*)d_out;

    const size_t qelems = (size_t)BATCH * NPTS * FDIM;
    half_t* ka = (half_t*)d_ws;                                  // 4 MB (fragment-major K/Q)
    half_t* vt = ka + qelems;                                    // 4 MB
    float* nrm = (float*)((char*)d_ws + 2 * qelems * sizeof(half_t));   // 128 KB
    half_t* part = (half_t*)(nrm + (size_t)BATCH * NPTS);

    const size_t part_elems = (size_t)BATCH * FDIM * NPTS;       // per split (fp16)
    const size_t l_elems    = (size_t)BATCH * NPTS;              // per split (f32)
    const size_t base_bytes = 2 * qelems * sizeof(half_t) + (size_t)BATCH * NPTS * sizeof(float);
    const size_t per_split  = part_elems * sizeof(half_t) + l_elems * sizeof(float);

    int split = 1;
    if (ws_size >= base_bytes + 4 * per_split)      split = 4;
    else if (ws_size >= base_bytes + 2 * per_split) split = 2;
    float* lbuf = (float*)(part + (size_t)split * part_elems);

    prep_kernel<<<640, 256, 0, stream>>>(x, w, ka, vt, nrm);

    if (split == 4) {
        flash_kernel<4><<<512, 256, 0, stream>>>(ka, vt, nrm, out, part, lbuf);
        combine_kernel<4><<<(BATCH * FDIM * NPTS) / 8 / 256, 256, 0, stream>>>(part, lbuf, out);
    } else if (split == 2) {
        flash_kernel<2><<<256, 256, 0, stream>>>(ka, vt, nrm, out, part, lbuf);
        combine_kernel<2><<<(BATCH * FDIM * NPTS) / 8 / 256, 256, 0, stream>>>(part, lbuf, out);
    } else {
        flash_kernel<1><<<128, 256, 0, stream>>>(ka, vt, nrm, out, nullptr, nullptr);
    }
}

// Round 18
// 80.622 us; speedup vs baseline: 1.1017x; 1.1017x over previous
//
#include <hip/hip_runtime.h>

#define BATCH 4
#define NPTS  8192
#define FDIM  64
#define BK    64
#define NT    (NPTS / BK)

typedef _Float16 half_t;
typedef half_t half8  __attribute__((ext_vector_type(8)));
typedef half_t half2v __attribute__((ext_vector_type(2)));
typedef float  f32x4  __attribute__((ext_vector_type(4)));
typedef float  f32x16 __attribute__((ext_vector_type(16)));
typedef unsigned uint4v __attribute__((ext_vector_type(4)));
typedef unsigned uint2v __attribute__((ext_vector_type(2)));

__device__ inline unsigned pkrtz(float a, float b) {
    return __builtin_bit_cast(unsigned, __builtin_amdgcn_cvt_pkrtz(a, b));
}
__device__ inline half2v h2(unsigned u) { return __builtin_bit_cast(half2v, u); }

// swap(a,b): new a = [a.lo | b.lo], new b = [a.hi | b.hi]  (lane halves)
__device__ inline uint2v plswap(unsigned a, unsigned b) {
    return __builtin_amdgcn_permlane32_swap(a, b, false, false);
}

// ---------------- prep (merged): blocks 0..511 = support GEMM, 512..639 = cast+norm.
// gemm: one thread per (b, n, o-block16); w[64][16] in LDS (broadcast f32x4 reads).
// cast: ka fragment-major (elem (n, f=f8*8+j) at ((n>>6)*8+f8)*512 + (n&63)*8 + j) + nrm.
__global__ __launch_bounds__(256) void prep_kernel(
    const float* __restrict__ x, const float* __restrict__ w,
    half_t* __restrict__ ka, half_t* __restrict__ vt, float* __restrict__ nrm)
{
    int t = threadIdx.x;
    if (blockIdx.x < 512) {
        __shared__ float wl[FDIM * 16];
        int ob  = blockIdx.x & 3;                     // o-block (wave-uniform)
        int nch = blockIdx.x >> 2;                    // 128 chunks of 256 n
        #pragma unroll
        for (int i = 0; i < 4; ++i) {                 // stage w[:, ob*16:+16]
            int idx = i * 256 + t;                    // idx = f*16 + j
            wl[idx] = w[(idx >> 4) * FDIM + ob * 16 + (idx & 15)];
        }
        __syncthreads();

        int gid = nch * 256 + t;                      // (b, n)
        int b = gid >> 13;
        int n = gid & (NPTS - 1);
        const float* xb = x + (size_t)b * FDIM * NPTS + n;

        float acc[16];
        #pragma unroll
        for (int o = 0; o < 16; ++o) acc[o] = 0.0f;
        #pragma unroll
        for (int f = 0; f < FDIM; ++f) {
            float xv = xb[(size_t)f * NPTS];          // coalesced; L2-served re-read
            const f32x4* wr = (const f32x4*)&wl[f * 16];   // broadcast, conflict-free
            f32x4 w0 = wr[0], w1 = wr[1], w2 = wr[2], w3 = wr[3];
            acc[ 0] += xv * w0[0]; acc[ 1] += xv * w0[1];
            acc[ 2] += xv * w0[2]; acc[ 3] += xv * w0[3];
            acc[ 4] += xv * w1[0]; acc[ 5] += xv * w1[1];
            acc[ 6] += xv * w1[2]; acc[ 7] += xv * w1[3];
            acc[ 8] += xv * w2[0]; acc[ 9] += xv * w2[1];
            acc[10] += xv * w2[2]; acc[11] += xv * w2[3];
            acc[12] += xv * w3[0]; acc[13] += xv * w3[1];
            acc[14] += xv * w3[2]; acc[15] += xv * w3[3];
        }
        half_t* vb = vt + (size_t)b * FDIM * NPTS + (size_t)ob * 16 * NPTS + n;
        #pragma unroll
        for (int o = 0; o < 16; ++o)
            vb[(size_t)o * NPTS] = (half_t)acc[o];    // coalesced across lanes
    } else {
        int gid = (blockIdx.x - 512) * 256 + t;       // (b, n)
        int b = gid >> 13;
        int n = gid & (NPTS - 1);
        const float* xb = x + (size_t)b * FDIM * NPTS + n;

        float nr = 0.0f;
        half_t* kab = ka + (size_t)(gid >> 6) * 4096 + (size_t)(gid & 63) * 8;
        #pragma unroll
        for (int f8 = 0; f8 < 8; ++f8) {
            half8 h;
            #pragma unroll
            for (int j = 0; j < 8; ++j) {
                float xv = xb[(size_t)(f8 * 8 + j) * NPTS];   // coalesced
                nr += xv * xv;
                h[j] = (half_t)xv;
            }
            *(half8*)(kab + f8 * 512) = h;                    // contiguous 16B
        }
        nrm[gid] = nr * 1.44269504f;
    }
}

// ---------------- flash attention (R15-proven best config, final):
// 32x32 MFMA, fixed-max softmax, split-KV; __launch_bounds__(256,2), grid 512,
// no setprio (R17: -13%). K/Q fragments direct from global (fragment-major),
// V in LDS dbuf. fp16 partials with qt-paired full-line stores.
// (R8: (256,3) breaks blk->XCD packing, FETCH->143MB. R11: (512,4) reg-caps -> spill.
// R16: LDS-free variant neutral. R14: in-wave reorder null. R6: global_load_lds
// bypasses L2 reuse.)
template<int SPLIT>
__global__ __launch_bounds__(256, 2) void flash_kernel(
    const half_t* __restrict__ qk, const half_t* __restrict__ vt,
    const float* __restrict__ nrm, float* __restrict__ out,
    half_t* __restrict__ part, float* __restrict__ lbuf)
{
    constexpr int TPS   = NT / SPLIT;
    constexpr int TOTAL = BATCH * SPLIT * (NPTS / 256);

    __shared__ half_t vl[2][BK * FDIM];    // V^T tile [o][granule-swizzled kv]

    int t    = threadIdx.x;
    int lane = t & 63;
    int l31  = lane & 31;
    int hi   = lane >> 5;
    int w    = t >> 6;                     // wave 0..3

    int blk0 = blockIdx.x;
    int blk  = (blk0 & 7) * (TOTAL / 8) + (blk0 >> 3);   // XCD swizzle (TOTAL%8==0)
    int qc   = blk & 31;                                 // q chunk (256 rows)
    int rest = blk >> 5;
    int s    = rest & (SPLIT - 1);
    int b    = rest / SPLIT;
    int qw   = qc * 256 + w * 64;                        // 64 q rows per wave

    const half_t* kg = qk + (size_t)b * NPTS * FDIM;     // fragment-major ka, batch b
    const half_t* vg = vt + (size_t)b * FDIM * NPTS;

    // Q B-frags (pre-scaled by log2 e) from fragment-major layout
    const half_t* qgb = kg + (size_t)(qw >> 6) * 4096 + (size_t)l31 * 8;
    half8 qf[2][4];
    #pragma unroll
    for (int qt = 0; qt < 2; ++qt)
        #pragma unroll
        for (int c = 0; c < 4; ++c) {
            qf[qt][c] = *(const half8*)(qgb + (c*2 + hi) * 512 + qt * 256);
            qf[qt][c] = qf[qt][c] * (half_t)1.44269504f;
        }

    float m2[2];
    #pragma unroll
    for (int qt = 0; qt < 2; ++qt)
        m2[qt] = nrm[(size_t)b * NPTS + qw + qt*32 + l31];

    // V staging: 512 16B-chunks, 2 per thread; swizzled LDS dest
    int r0 = t >> 3, g0 = t & 7;
    int r1 = r0 + 32;
    int li0 = r0 * FDIM + ((g0 ^ (r0 & 7)) * 8);
    int li1 = r1 * FDIM + ((g0 ^ (r1 & 7)) * 8);

    int kb0 = s * TPS * BK;
    half8 s2 = *(const half8*)(vg + (size_t)r0 * NPTS + kb0 + g0*8);
    half8 s3 = *(const half8*)(vg + (size_t)r1 * NPTS + kb0 + g0*8);

    // K fragments for tile 0 (direct global, coalesced)
    half8 kf[2][4];
    {
        const half_t* kgb = kg + (size_t)(kb0 >> 6) * 4096 + (size_t)l31 * 8;
        #pragma unroll
        for (int ct = 0; ct < 2; ++ct)
            #pragma unroll
            for (int c = 0; c < 4; ++c)
                kf[ct][c] = *(const half8*)(kgb + (c*2 + hi) * 512 + ct * 256);
    }

    f32x16 O[2][2];
    #pragma unroll
    for (int ot = 0; ot < 2; ++ot)
        #pragma unroll
        for (int qt = 0; qt < 2; ++qt)
            #pragma unroll
            for (int r = 0; r < 16; ++r) O[ot][qt][r] = 0.0f;
    float lsum[2] = {0.0f, 0.0f};

    for (int tt = 0; tt < TPS; ++tt) {
        half_t* vlb = vl[tt & 1];
        *(half8*)(vlb + li0) = s2;
        *(half8*)(vlb + li1) = s3;
        if (tt + 1 < TPS) {                // V prefetch stays in flight across barrier
            int kb = kb0 + (tt + 1) * BK;
            s2 = *(const half8*)(vg + (size_t)r0 * NPTS + kb + g0*8);
            s3 = *(const half8*)(vg + (size_t)r1 * NPTS + kb + g0*8);
        }
        __syncthreads();                   // V writes visible; prev-tile readers done

        const half_t* kgbn = kg + (size_t)((kb0 + (tt + 1) * BK) >> 6) * 4096 + (size_t)l31 * 8;

        // ---- S^T = K x Q^T for BOTH ct (C preset to -m2 folds max subtraction)
        f32x16 S[2][2];
        #pragma unroll
        for (int ct = 0; ct < 2; ++ct)
            #pragma unroll
            for (int r = 0; r < 16; ++r) { S[ct][0][r] = -m2[0]; S[ct][1][r] = -m2[1]; }
        #pragma unroll
        for (int ct = 0; ct < 2; ++ct)
            #pragma unroll
            for (int c = 0; c < 4; ++c) {
                S[ct][0] = __builtin_amdgcn_mfma_f32_32x32x16_f16(kf[ct][c], qf[0][c], S[ct][0], 0, 0, 0);
                S[ct][1] = __builtin_amdgcn_mfma_f32_32x32x16_f16(kf[ct][c], qf[1][c], S[ct][1], 0, 0, 0);
            }
        // refill kf (both ct) for next tile; L2 latency hides under exp/pack + PV
        if (tt + 1 < TPS) {
            #pragma unroll
            for (int ct = 0; ct < 2; ++ct)
                #pragma unroll
                for (int c = 0; c < 4; ++c)
                    kf[ct][c] = *(const half8*)(kgbn + (c*2 + hi) * 512 + ct * 256);
        }

        #pragma unroll
        for (int ct = 0; ct < 2; ++ct) {
            // ---- p = exp2(S); pack to fp16 (RTZ saturates); lsum via packed fp16 adds
            unsigned pk[2][8];
            #pragma unroll
            for (int qt = 0; qt < 2; ++qt) {
                #pragma unroll
                for (int rr = 0; rr < 8; ++rr)
                    pk[qt][rr] = pkrtz(__builtin_amdgcn_exp2f(S[ct][qt][2*rr]),
                                       __builtin_amdgcn_exp2f(S[ct][qt][2*rr+1]));
                half2v s2v = ((h2(pk[qt][0]) + h2(pk[qt][1])) + (h2(pk[qt][2]) + h2(pk[qt][3])))
                           + ((h2(pk[qt][4]) + h2(pk[qt][5])) + (h2(pk[qt][6]) + h2(pk[qt][7])));
                lsum[qt] += (float)s2v[0] + (float)s2v[1];
            }

            // ---- O^T += V^T x P^T for kt = 2ct, 2ct+1 (pk for this ct only)
            #pragma unroll
            for (int ktl = 0; ktl < 2; ++ktl) {
                const int kt = ct * 2 + ktl, i0 = ktl * 4;
                half8 pb[2];
                #pragma unroll
                for (int qt = 0; qt < 2; ++qt) {
                    uint2v r02 = plswap(pk[qt][i0+0], pk[qt][i0+2]);
                    uint2v r13 = plswap(pk[qt][i0+1], pk[qt][i0+3]);
                    uint4v uu; uu[0] = r02[0]; uu[1] = r13[0]; uu[2] = r02[1]; uu[3] = r13[1];
                    pb[qt] = __builtin_bit_cast(half8, uu);
                }
                int vrow0 = l31, vrow1 = 32 + l31;
                half8 vf0 = *(const half8*)(vlb + vrow0 * FDIM + (((2*kt + hi) ^ (vrow0 & 7)) * 8));
                half8 vf1 = *(const half8*)(vlb + vrow1 * FDIM + (((2*kt + hi) ^ (vrow1 & 7)) * 8));
                O[0][0] = __builtin_amdgcn_mfma_f32_32x32x16_f16(vf0, pb[0], O[0][0], 0, 0, 0);
                O[0][1] = __builtin_amdgcn_mfma_f32_32x32x16_f16(vf0, pb[1], O[0][1], 0, 0, 0);
                O[1][0] = __builtin_amdgcn_mfma_f32_32x32x16_f16(vf1, pb[0], O[1][0], 0, 0, 0);
                O[1][1] = __builtin_amdgcn_mfma_f32_32x32x16_f16(vf1, pb[1], O[1][1], 0, 0, 0);
            }
        }
    }

    // final row-sum reduce across lane halves (cols duplicated at l31 / l31+32)
    lsum[0] += __shfl_xor(lsum[0], 32);
    lsum[1] += __shfl_xor(lsum[1], 32);

    if constexpr (SPLIT == 1) {
        float inv[2] = {1.0f / lsum[0], 1.0f / lsum[1]};
        size_t ob = (size_t)b * FDIM * NPTS;
        #pragma unroll
        for (int qt = 0; qt < 2; ++qt)
            #pragma unroll
            for (int ot = 0; ot < 2; ++ot)
                #pragma unroll
                for (int r = 0; r < 16; ++r) {
                    int o = ot*32 + (r & 3) + 8*(r >> 2) + 4*hi;
                    out[ob + (size_t)o * NPTS + qw + qt*32 + l31] = O[ot][qt][r] * inv[qt];
                }
    } else {
        // fp16 partials; qt=0/qt=1 stores adjacent -> 64 consecutive fp16 (128B line)
        half_t* pbase = part + (size_t)(s * BATCH + b) * FDIM * NPTS;
        #pragma unroll
        for (int ot = 0; ot < 2; ++ot)
            #pragma unroll
            for (int r = 0; r < 16; ++r) {
                int o = ot*32 + (r & 3) + 8*(r >> 2) + 4*hi;
                half_t* po = pbase + (size_t)o * NPTS + qw + l31;
                po[0]  = (half_t)O[ot][0][r];
                po[32] = (half_t)O[ot][1][r];
            }
        if (hi == 0) {
            float* lb = lbuf + (size_t)(s * BATCH + b) * NPTS + qw;
            lb[l31]      = lsum[0];
            lb[32 + l31] = lsum[1];
        }
    }
}

// ---------------- combine: out = sum_s part_s / sum_s l_s (shared fixed max -> linear)
template<int SPLIT>
__global__ __launch_bounds__(256) void combine_kernel(
    const half_t* __restrict__ part, const float* __restrict__ lbuf,
    float* __restrict__ out)
{
    int gid  = blockIdx.x * 256 + threadIdx.x;    // B*F*N/8 threads
    int q8   = gid & (NPTS/8 - 1);
    int rest = gid >> 10;                         // b*64 + o
    int b    = rest >> 6;
    int o    = rest & 63;
    size_t ro = (size_t)rest * NPTS + (size_t)q8 * 8;

    float acc[8], ls[8];
    #pragma unroll
    for (int j = 0; j < 8; ++j) { acc[j] = 0.0f; ls[j] = 0.0f; }
    #pragma unroll
    for (int s = 0; s < SPLIT; ++s) {
        half8 pv = *(const half8*)(part + (size_t)(s * BATCH + b) * FDIM * NPTS
                                        + (size_t)o * NPTS + (size_t)q8 * 8);
        const float* lb = lbuf + (size_t)(s * BATCH + b) * NPTS + (size_t)q8 * 8;
        #pragma unroll
        for (int j = 0; j < 8; ++j) { acc[j] += (float)pv[j]; ls[j] += lb[j]; }
    }
    #pragma unroll
    for (int j = 0; j < 8; ++j) acc[j] /= ls[j];
    *(f32x4*)(out + ro)     = *(f32x4*)&acc[0];
    *(f32x4*)(out + ro + 4) = *(f32x4*)&acc[4];
}

extern "C" void kernel_launch(void* const* d_in, const int* in_sizes, int n_in,
                              void* d_out, int out_size, void* d_ws, size_t ws_size,
                              hipStream_t stream) {
    (void)in_sizes; (void)n_in; (void)out_size;
    const float* x = (const float*)d_in[0];
    const float* w = (const float*)d_in[1];
    float* out = (float*)d_out;

    const size_t qelems = (size_t)BATCH * NPTS * FDIM;
    half_t* ka = (half_t*)d_ws;                                  // 4 MB (fragment-major K/Q)
    half_t* vt = ka + qelems;                                    // 4 MB
    float* nrm = (float*)((char*)d_ws + 2 * qelems * sizeof(half_t));   // 128 KB
    half_t* part = (half_t*)(nrm + (size_t)BATCH * NPTS);

    const size_t part_elems = (size_t)BATCH * FDIM * NPTS;       // per split (fp16)
    const size_t l_elems    = (size_t)BATCH * NPTS;              // per split (f32)
    const size_t base_bytes = 2 * qelems * sizeof(half_t) + (size_t)BATCH * NPTS * sizeof(float);
    const size_t per_split  = part_elems * sizeof(half_t) + l_elems * sizeof(float);

    int split = 1;
    if (ws_size >= base_bytes + 4 * per_split)      split = 4;
    else if (ws_size >= base_bytes + 2 * per_split) split = 2;
    float* lbuf = (float*)(part + (size_t)split * part_elems);

    prep_kernel<<<640, 256, 0, stream>>>(x, w, ka, vt, nrm);

    if (split == 4) {
        flash_kernel<4><<<512, 256, 0, stream>>>(ka, vt, nrm, out, part, lbuf);
        combine_kernel<4><<<(BATCH * FDIM * NPTS) / 8 / 256, 256, 0, stream>>>(part, lbuf, out);
    } else if (split == 2) {
        flash_kernel<2><<<256, 256, 0, stream>>>(ka, vt, nrm, out, part, lbuf);
        combine_kernel<2><<<(BATCH * FDIM * NPTS) / 8 / 256, 256, 0, stream>>>(part, lbuf, out);
    } else {
        flash_kernel<1><<<128, 256, 0, stream>>>(ka, vt, nrm, out, nullptr, nullptr);
    }
}